// Round 1
// baseline (3499.554 us; speedup 1.0000x reference)
//
#include <hip/hip_runtime.h>
#include <math.h>

namespace {

constexpr int B   = 2;
constexpr int S   = 2048;
constexpr int D   = 2048;
constexpr int NH  = 16;
constexpr int NKV = 4;
constexpr int HD  = 128;
constexpr int GRP = NH / NKV;   // 4

// ---------------------------------------------------------------------------
// SGEMM: C = A @ B, row-major. M,N multiples of 128; K multiple of 16.
// 256 threads, BM=BN=128, BK=16, 8x8 micro-tile per thread.
// ---------------------------------------------------------------------------
constexpr int BM = 128, BN = 128, BK = 16, TM = 8, TN = 8;

__global__ __launch_bounds__(256)
void sgemm_kernel(const float* __restrict__ A, const float* __restrict__ Bm,
                  float* __restrict__ C, int M, int N, int K)
{
    // As transposed [k][m], padded +4 so the 4 scalar transposed stores are
    // 2-way (free) and float4 compute reads stay 16B-aligned (132 % 4 == 0).
    __shared__ float As[BK][BM + 4];
    __shared__ float Bs[BK][BN];

    const int t  = threadIdx.x;
    const int tx = t & 15;         // 0..15 -> N direction
    const int ty = t >> 4;         // 0..15 -> M direction
    const int row0 = blockIdx.y * BM;
    const int col0 = blockIdx.x * BN;

    const int am = t >> 2;         // 0..63 (A row within tile; +64 on 2nd iter)
    const int ak = (t & 3) << 2;   // 0,4,8,12
    const int bk = t >> 5;         // 0..7  (B row within tile; +8 on 2nd iter)
    const int bn = (t & 31) << 2;  // 0..124

    float acc[TM][TN] = {};

    for (int k0 = 0; k0 < K; k0 += BK) {
#pragma unroll
        for (int i = 0; i < 2; ++i) {
            const int m = am + i * 64;
            const float4 va = *reinterpret_cast<const float4*>(
                &A[(size_t)(row0 + m) * K + (k0 + ak)]);
            As[ak + 0][m] = va.x;
            As[ak + 1][m] = va.y;
            As[ak + 2][m] = va.z;
            As[ak + 3][m] = va.w;
        }
#pragma unroll
        for (int i = 0; i < 2; ++i) {
            const int kk = bk + i * 8;
            *reinterpret_cast<float4*>(&Bs[kk][bn]) =
                *reinterpret_cast<const float4*>(
                    &Bm[(size_t)(k0 + kk) * N + (col0 + bn)]);
        }
        __syncthreads();

#pragma unroll
        for (int k = 0; k < BK; ++k) {
            float af[TM], bf[TN];
            {
                float4 v = *reinterpret_cast<const float4*>(&As[k][ty * TM]);
                af[0] = v.x; af[1] = v.y; af[2] = v.z; af[3] = v.w;
                v = *reinterpret_cast<const float4*>(&As[k][ty * TM + 4]);
                af[4] = v.x; af[5] = v.y; af[6] = v.z; af[7] = v.w;
            }
            {
                float4 v = *reinterpret_cast<const float4*>(&Bs[k][tx * TN]);
                bf[0] = v.x; bf[1] = v.y; bf[2] = v.z; bf[3] = v.w;
                v = *reinterpret_cast<const float4*>(&Bs[k][tx * TN + 4]);
                bf[4] = v.x; bf[5] = v.y; bf[6] = v.z; bf[7] = v.w;
            }
#pragma unroll
            for (int i = 0; i < TM; ++i)
#pragma unroll
                for (int j = 0; j < TN; ++j)
                    acc[i][j] = fmaf(af[i], bf[j], acc[i][j]);
        }
        __syncthreads();
    }

#pragma unroll
    for (int i = 0; i < TM; ++i) {
        const int m = row0 + ty * TM + i;
#pragma unroll
        for (int j = 0; j < TN; j += 4) {
            const float4 v = make_float4(acc[i][j], acc[i][j + 1],
                                         acc[i][j + 2], acc[i][j + 3]);
            *reinterpret_cast<float4*>(&C[(size_t)m * N + col0 + tx * TN + j]) = v;
        }
    }
}

// ---------------------------------------------------------------------------
// RoPE, in place over a (rows, n_heads, 128) fp32 tensor. One thread per
// (row, head, i) pair with i in [0,64): rotates (x[i], x[i+64]).
// ---------------------------------------------------------------------------
__global__ __launch_bounds__(256)
void rope_kernel(float* __restrict__ X, int n_heads, int total_pairs)
{
    const int idx = blockIdx.x * blockDim.x + threadIdx.x;
    if (idx >= total_pairs) return;
    const int i    = idx & 63;
    const int rest = idx >> 6;
    const int head = rest % n_heads;
    const int row  = rest / n_heads;     // b*S + s
    const int pos  = row & (S - 1);      // S is a power of two

    // inv_freq = 10000^(-i/64) = exp(-ln(10000) * i/64)
    const float inv = expf(-9.2103403719761836f * (float)i * (1.0f / 64.0f));
    const float fr  = (float)pos * inv;
    float sn, cs;
    sincosf(fr, &sn, &cs);

    const size_t base = ((size_t)row * n_heads + head) * HD + i;
    const float x1 = X[base], x2 = X[base + 64];
    X[base]      = fmaf(x1, cs, -x2 * sn);   // x1*cos - x2*sin
    X[base + 64] = fmaf(x2, cs,  x1 * sn);   // x2*cos + x1*sin
}

// ---------------------------------------------------------------------------
// Flash attention (causal, GQA). One block per (q-tile of 32 rows, b*H).
// fp32 throughout, online softmax. 256 threads.
// ---------------------------------------------------------------------------
constexpr int QT = 32, KT = 32;
constexpr float INV_SQRT_HD = 0.08838834764831845f;  // 1/sqrt(128)

__global__ __launch_bounds__(256)
void flash_kernel(const float* __restrict__ Qm, const float* __restrict__ Km,
                  const float* __restrict__ Vm, float* __restrict__ Om)
{
    __shared__ float Qs[QT][HD + 4];
    __shared__ float Ks[KT][HD + 4];
    __shared__ float Vs[KT][HD + 4];
    __shared__ float Ps[QT][36];
    __shared__ float Ss[QT];
    __shared__ float Ls[QT];

    const int t  = threadIdx.x;
    const int bh = blockIdx.y;
    const int b  = bh / NH;
    const int h  = bh % NH;
    const int u  = h / GRP;              // kv head
    const int q0 = blockIdx.x * QT;

    // ---- load Q tile, pre-scaled by 1/sqrt(HD) ----
    {
        const int r = t >> 5;            // 0..7
        const int c = (t & 31) << 2;     // 0..124
#pragma unroll
        for (int i = 0; i < QT; i += 8) {
            float4 v = *reinterpret_cast<const float4*>(
                &Qm[(((size_t)(b * S + q0 + r + i)) * NH + h) * HD + c]);
            v.x *= INV_SQRT_HD; v.y *= INV_SQRT_HD;
            v.z *= INV_SQRT_HD; v.w *= INV_SQRT_HD;
            *reinterpret_cast<float4*>(&Qs[r + i][c]) = v;
        }
    }

    // score phase: row sr (0..31), 4 cols {sc, sc+8, sc+16, sc+24}
    const int sr = t >> 3;
    const int sc = t & 7;
    // pv phase: rows {pr, pr+1}, 8 dims starting at pd
    const int pr = (t >> 4) << 1;
    const int pd = (t & 15) << 3;

    float m_run = -INFINITY, l_run = 0.f;
    float o0[8] = {}, o1[8] = {};

    const int nkt = q0 / KT + 1;     // causal: only tiles at/below diagonal
    for (int kt = 0; kt < nkt; ++kt) {
        const int k0 = kt * KT;
        {
            const int r = t >> 5;
            const int c = (t & 31) << 2;
#pragma unroll
            for (int i = 0; i < KT; i += 8) {
                const size_t base =
                    (((size_t)(b * S + k0 + r + i)) * NKV + u) * HD + c;
                *reinterpret_cast<float4*>(&Ks[r + i][c]) =
                    *reinterpret_cast<const float4*>(&Km[base]);
                *reinterpret_cast<float4*>(&Vs[r + i][c]) =
                    *reinterpret_cast<const float4*>(&Vm[base]);
            }
        }
        __syncthreads();

        // ---- scores: S[sr][sc+8j] = (Q/sqrt(HD)) . K ----
        float s4[4] = {0.f, 0.f, 0.f, 0.f};
#pragma unroll
        for (int k4 = 0; k4 < HD; k4 += 4) {
            const float4 qv = *reinterpret_cast<const float4*>(&Qs[sr][k4]);
#pragma unroll
            for (int j = 0; j < 4; ++j) {
                const float4 kv =
                    *reinterpret_cast<const float4*>(&Ks[sc + 8 * j][k4]);
                s4[j] = fmaf(qv.x, kv.x, s4[j]);
                s4[j] = fmaf(qv.y, kv.y, s4[j]);
                s4[j] = fmaf(qv.z, kv.z, s4[j]);
                s4[j] = fmaf(qv.w, kv.w, s4[j]);
            }
        }
        if (k0 + KT > q0) {   // diagonal tile: mask kg > qg
#pragma unroll
            for (int j = 0; j < 4; ++j)
                if (k0 + sc + 8 * j > q0 + sr) s4[j] = -1e30f;
        }

        // ---- online softmax (8 lanes per row, reduce via shfl_xor) ----
        float mx = fmaxf(fmaxf(s4[0], s4[1]), fmaxf(s4[2], s4[3]));
#pragma unroll
        for (int off = 1; off < 8; off <<= 1)
            mx = fmaxf(mx, __shfl_xor(mx, off, 64));
        const float m_new = fmaxf(m_run, mx);
        const float resc  = expf(m_run - m_new);   // exp(-inf)=0 first time
        float p[4], rs = 0.f;
#pragma unroll
        for (int j = 0; j < 4; ++j) { p[j] = expf(s4[j] - m_new); rs += p[j]; }
#pragma unroll
        for (int off = 1; off < 8; off <<= 1)
            rs += __shfl_xor(rs, off, 64);
        l_run = l_run * resc + rs;
        m_run = m_new;
#pragma unroll
        for (int j = 0; j < 4; ++j) Ps[sr][sc + 8 * j] = p[j];
        if ((t & 7) == 0) Ss[sr] = resc;
        __syncthreads();

        // ---- PV: O[pr..pr+1][pd..pd+7] += P . V, with rescale ----
        const float ss0 = Ss[pr], ss1 = Ss[pr + 1];
#pragma unroll
        for (int j = 0; j < 8; ++j) { o0[j] *= ss0; o1[j] *= ss1; }
#pragma unroll
        for (int c = 0; c < KT; c += 4) {
            const float4 p0 = *reinterpret_cast<const float4*>(&Ps[pr][c]);
            const float4 p1 = *reinterpret_cast<const float4*>(&Ps[pr + 1][c]);
#pragma unroll
            for (int cc = 0; cc < 4; ++cc) {
                const float4 va =
                    *reinterpret_cast<const float4*>(&Vs[c + cc][pd]);
                const float4 vb =
                    *reinterpret_cast<const float4*>(&Vs[c + cc][pd + 4]);
                const float w0 = (cc == 0) ? p0.x : (cc == 1) ? p0.y
                               : (cc == 2) ? p0.z : p0.w;
                const float w1 = (cc == 0) ? p1.x : (cc == 1) ? p1.y
                               : (cc == 2) ? p1.z : p1.w;
                o0[0] = fmaf(w0, va.x, o0[0]); o0[1] = fmaf(w0, va.y, o0[1]);
                o0[2] = fmaf(w0, va.z, o0[2]); o0[3] = fmaf(w0, va.w, o0[3]);
                o0[4] = fmaf(w0, vb.x, o0[4]); o0[5] = fmaf(w0, vb.y, o0[5]);
                o0[6] = fmaf(w0, vb.z, o0[6]); o0[7] = fmaf(w0, vb.w, o0[7]);
                o1[0] = fmaf(w1, va.x, o1[0]); o1[1] = fmaf(w1, va.y, o1[1]);
                o1[2] = fmaf(w1, va.z, o1[2]); o1[3] = fmaf(w1, va.w, o1[3]);
                o1[4] = fmaf(w1, vb.x, o1[4]); o1[5] = fmaf(w1, vb.y, o1[5]);
                o1[6] = fmaf(w1, vb.z, o1[6]); o1[7] = fmaf(w1, vb.w, o1[7]);
            }
        }
        __syncthreads();
    }

    if ((t & 7) == 0) Ls[sr] = l_run;
    __syncthreads();
    const float inv0 = 1.f / Ls[pr];
    const float inv1 = 1.f / Ls[pr + 1];
    {
        float* dst0 = &Om[(((size_t)(b * S + q0 + pr))     * NH + h) * HD + pd];
        float* dst1 = &Om[(((size_t)(b * S + q0 + pr + 1)) * NH + h) * HD + pd];
        *reinterpret_cast<float4*>(dst0) =
            make_float4(o0[0]*inv0, o0[1]*inv0, o0[2]*inv0, o0[3]*inv0);
        *reinterpret_cast<float4*>(dst0 + 4) =
            make_float4(o0[4]*inv0, o0[5]*inv0, o0[6]*inv0, o0[7]*inv0);
        *reinterpret_cast<float4*>(dst1) =
            make_float4(o1[0]*inv1, o1[1]*inv1, o1[2]*inv1, o1[3]*inv1);
        *reinterpret_cast<float4*>(dst1 + 4) =
            make_float4(o1[4]*inv1, o1[5]*inv1, o1[6]*inv1, o1[7]*inv1);
    }
}

} // anonymous namespace

// ---------------------------------------------------------------------------
// Launch: QKV GEMMs -> RoPE(q,k) -> flash attention -> O projection.
// Workspace layout (floats): q[4096*2048] k[4096*512] v[4096*512]
//                            attn[4096*2048]  (~84 MB total)
// ---------------------------------------------------------------------------
extern "C" void kernel_launch(void* const* d_in, const int* in_sizes, int n_in,
                              void* d_out, int out_size, void* d_ws, size_t ws_size,
                              hipStream_t stream)
{
    const float* hidden = (const float*)d_in[0];
    // d_in[1] = attention_mask: deterministic causal mask -> applied analytically
    const float* Wq = (const float*)d_in[2];
    const float* Wk = (const float*)d_in[3];
    const float* Wv = (const float*)d_in[4];
    const float* Wo = (const float*)d_in[5];   // (H, HD, D) == (H*HD, D) flat
    float* out = (float*)d_out;

    float* ws = (float*)d_ws;
    const int MR = B * S;                       // 4096 rows
    float* q_ws    = ws;
    float* k_ws    = q_ws + (size_t)MR * NH * HD;
    float* v_ws    = k_ws + (size_t)MR * NKV * HD;
    float* attn_ws = v_ws + (size_t)MR * NKV * HD;

    const dim3 blk(256);

    sgemm_kernel<<<dim3((NH * HD) / BN, MR / BM), blk, 0, stream>>>(
        hidden, Wq, q_ws, MR, NH * HD, D);
    sgemm_kernel<<<dim3((NKV * HD) / BN, MR / BM), blk, 0, stream>>>(
        hidden, Wk, k_ws, MR, NKV * HD, D);
    sgemm_kernel<<<dim3((NKV * HD) / BN, MR / BM), blk, 0, stream>>>(
        hidden, Wv, v_ws, MR, NKV * HD, D);

    const int qpairs = MR * NH * 64;    // 4,194,304
    const int kpairs = MR * NKV * 64;   // 1,048,576
    rope_kernel<<<dim3((qpairs + 255) / 256), blk, 0, stream>>>(q_ws, NH, qpairs);
    rope_kernel<<<dim3((kpairs + 255) / 256), blk, 0, stream>>>(k_ws, NKV, kpairs);

    flash_kernel<<<dim3(S / QT, B * NH), blk, 0, stream>>>(q_ws, k_ws, v_ws, attn_ws);

    sgemm_kernel<<<dim3(D / BN, MR / BM), blk, 0, stream>>>(
        attn_ws, Wo, out, MR, D, D);
}

// Round 3
// 1868.767 us; speedup vs baseline: 1.8727x; 1.8727x over previous
//
#include <hip/hip_runtime.h>
#include <math.h>

namespace {

constexpr int B   = 2;
constexpr int S   = 2048;
constexpr int D   = 2048;
constexpr int NH  = 16;
constexpr int NKV = 4;
constexpr int HD  = 128;
constexpr int GRP = NH / NKV;   // 4

typedef __attribute__((ext_vector_type(8))) short  short8;
typedef __attribute__((ext_vector_type(4))) float  f32x4;

__device__ inline unsigned short f2bf(float f) {
    unsigned u = __float_as_uint(f);
    u = (u + 0x7FFFu + ((u >> 16) & 1u)) >> 16;   // RNE
    return (unsigned short)u;
}
__device__ inline float bf2f(unsigned short h) {
    return __uint_as_float((unsigned)h << 16);
}

// ---------------------------------------------------------------------------
// SGEMM: C = A @ B, row-major (fp32 path for projections, unchanged).
// ---------------------------------------------------------------------------
constexpr int BM = 128, BN = 128, BK = 16, TM = 8, TN = 8;

__global__ __launch_bounds__(256)
void sgemm_kernel(const float* __restrict__ A, const float* __restrict__ Bm,
                  float* __restrict__ C, int M, int N, int K)
{
    __shared__ float As[BK][BM + 4];
    __shared__ float Bs[BK][BN];

    const int t  = threadIdx.x;
    const int tx = t & 15;
    const int ty = t >> 4;
    const int row0 = blockIdx.y * BM;
    const int col0 = blockIdx.x * BN;

    const int am = t >> 2;
    const int ak = (t & 3) << 2;
    const int bk = t >> 5;
    const int bn = (t & 31) << 2;

    float acc[TM][TN] = {};

    for (int k0 = 0; k0 < K; k0 += BK) {
#pragma unroll
        for (int i = 0; i < 2; ++i) {
            const int m = am + i * 64;
            const float4 va = *reinterpret_cast<const float4*>(
                &A[(size_t)(row0 + m) * K + (k0 + ak)]);
            As[ak + 0][m] = va.x;
            As[ak + 1][m] = va.y;
            As[ak + 2][m] = va.z;
            As[ak + 3][m] = va.w;
        }
#pragma unroll
        for (int i = 0; i < 2; ++i) {
            const int kk = bk + i * 8;
            *reinterpret_cast<float4*>(&Bs[kk][bn]) =
                *reinterpret_cast<const float4*>(
                    &Bm[(size_t)(k0 + kk) * N + (col0 + bn)]);
        }
        __syncthreads();

#pragma unroll
        for (int k = 0; k < BK; ++k) {
            float af[TM], bf[TN];
            {
                float4 v = *reinterpret_cast<const float4*>(&As[k][ty * TM]);
                af[0] = v.x; af[1] = v.y; af[2] = v.z; af[3] = v.w;
                v = *reinterpret_cast<const float4*>(&As[k][ty * TM + 4]);
                af[4] = v.x; af[5] = v.y; af[6] = v.z; af[7] = v.w;
            }
            {
                float4 v = *reinterpret_cast<const float4*>(&Bs[k][tx * TN]);
                bf[0] = v.x; bf[1] = v.y; bf[2] = v.z; bf[3] = v.w;
                v = *reinterpret_cast<const float4*>(&Bs[k][tx * TN + 4]);
                bf[4] = v.x; bf[5] = v.y; bf[6] = v.z; bf[7] = v.w;
            }
#pragma unroll
            for (int i = 0; i < TM; ++i)
#pragma unroll
                for (int j = 0; j < TN; ++j)
                    acc[i][j] = fmaf(af[i], bf[j], acc[i][j]);
        }
        __syncthreads();
    }

#pragma unroll
    for (int i = 0; i < TM; ++i) {
        const int m = row0 + ty * TM + i;
#pragma unroll
        for (int j = 0; j < TN; j += 4) {
            const float4 v = make_float4(acc[i][j], acc[i][j + 1],
                                         acc[i][j + 2], acc[i][j + 3]);
            *reinterpret_cast<float4*>(&C[(size_t)m * N + col0 + tx * TN + j]) = v;
        }
    }
}

// ---------------------------------------------------------------------------
// RoPE + split-cast fp32 -> (bf16 hi, bf16 lo), head-major [B][nh][S][HD].
// ---------------------------------------------------------------------------
__global__ __launch_bounds__(256)
void rope_cast_kernel(const float* __restrict__ X,
                      unsigned short* __restrict__ Yh,
                      unsigned short* __restrict__ Yl,
                      int n_heads, int total_pairs, float scale)
{
    const int idx = blockIdx.x * blockDim.x + threadIdx.x;
    if (idx >= total_pairs) return;
    const int i    = idx & 63;
    const int rest = idx >> 6;
    const int head = rest % n_heads;
    const int row  = rest / n_heads;     // b*S + s
    const int s    = row & (S - 1);
    const int b    = row >> 11;

    const float inv = expf(-9.2103403719761836f * (float)i * (1.0f / 64.0f));
    const float fr  = (float)s * inv;
    float sn, cs;
    sincosf(fr, &sn, &cs);

    const float* src = X + (size_t)row * (n_heads * HD) + head * HD + i;
    const float x1 = src[0], x2 = src[64];
    const float y1 = (x1 * cs - x2 * sn) * scale;
    const float y2 = (x2 * cs + x1 * sn) * scale;

    const unsigned short h1 = f2bf(y1), h2 = f2bf(y2);
    const unsigned short l1 = f2bf(y1 - bf2f(h1)), l2 = f2bf(y2 - bf2f(h2));

    const size_t o = ((size_t)(b * n_heads + head) * S + s) * HD + i;
    Yh[o] = h1; Yh[o + 64] = h2;
    Yl[o] = l1; Yl[o + 64] = l2;
}

// ---------------------------------------------------------------------------
// V: fp32 [B*S][NKV][HD] -> bf16 hi/lo transposed [B][NKV][HD][S].
// ---------------------------------------------------------------------------
__global__ __launch_bounds__(256)
void vcast_kernel(const float* __restrict__ V,
                  unsigned short* __restrict__ Yh,
                  unsigned short* __restrict__ Yl)
{
    __shared__ unsigned short th[64][68];
    __shared__ unsigned short tl[64][68];
    const int t  = threadIdx.x;
    const int s0 = blockIdx.x * 64, dv0 = blockIdx.y * 64;
    const int b  = blockIdx.z >> 2, u = blockIdx.z & 3;

#pragma unroll
    for (int i = 0; i < 4; ++i) {
        const int sr = (t >> 4) + i * 16;
        const int dc = (t & 15) * 4;
        const float4 v = *reinterpret_cast<const float4*>(
            &V[((size_t)(b * S + s0 + sr) * NKV + u) * HD + dv0 + dc]);
        const unsigned short hx = f2bf(v.x), hy = f2bf(v.y),
                             hz = f2bf(v.z), hw = f2bf(v.w);
        th[sr][dc + 0] = hx; tl[sr][dc + 0] = f2bf(v.x - bf2f(hx));
        th[sr][dc + 1] = hy; tl[sr][dc + 1] = f2bf(v.y - bf2f(hy));
        th[sr][dc + 2] = hz; tl[sr][dc + 2] = f2bf(v.z - bf2f(hz));
        th[sr][dc + 3] = hw; tl[sr][dc + 3] = f2bf(v.w - bf2f(hw));
    }
    __syncthreads();
#pragma unroll
    for (int i = 0; i < 4; ++i) {
        const int dr = (t >> 4) + i * 16;
        const int sc = (t & 15) * 4;
        ushort4 oh, ol;
        oh.x = th[sc + 0][dr]; ol.x = tl[sc + 0][dr];
        oh.y = th[sc + 1][dr]; ol.y = tl[sc + 1][dr];
        oh.z = th[sc + 2][dr]; ol.z = tl[sc + 2][dr];
        oh.w = th[sc + 3][dr]; ol.w = tl[sc + 3][dr];
        const size_t o = ((size_t)(b * NKV + u) * HD + dv0 + dr) * S + s0 + sc;
        *reinterpret_cast<ushort4*>(&Yh[o]) = oh;
        *reinterpret_cast<ushort4*>(&Yl[o]) = ol;
    }
}

// ---------------------------------------------------------------------------
// Flash attention, double-bf16 (hi/lo) MFMA, fp32 online softmax.
// Block = 4 waves; each wave owns 16 q-rows of a 64-row Q tile. KT=32.
// QK^T = Qh.Kh + Qh.Kl + Ql.Kh ; PV = Ph.Vh + Ph.Vl + Pl.Vh.
// ---------------------------------------------------------------------------
constexpr int QTILE = 64, KT = 32;

__global__ __launch_bounds__(256)
void flash_mfma_kernel(const unsigned short* __restrict__ Qh,
                       const unsigned short* __restrict__ Ql,
                       const unsigned short* __restrict__ Kh,
                       const unsigned short* __restrict__ Kl,
                       const unsigned short* __restrict__ Vh,
                       const unsigned short* __restrict__ Vl,
                       float* __restrict__ Om)
{
    // ushort units: KsH [0,4096) KsL [4096,8192) VtH [8192,13312)
    // VtL [13312,18432) PH [18432,20992) PL [20992,23552)
    // Q staging transient uses [0,16384).
    __shared__ alignas(16) unsigned short smem[23552];
    unsigned short* KsH = smem;
    unsigned short* KsL = smem + 4096;
    unsigned short* VtH = smem + 8192;
    unsigned short* VtL = smem + 13312;
    unsigned short* PH  = smem + 18432;
    unsigned short* PL  = smem + 20992;

    const int t  = threadIdx.x;
    const int w  = t >> 6;
    const int ln = t & 63;
    const int lg = ln >> 4;             // 0..3
    const int lc = ln & 15;             // 0..15

    const int qt = (int)gridDim.x - 1 - (int)blockIdx.x;   // heavy tiles first
    const int q0 = qt * QTILE;
    const int bh = blockIdx.y;
    const int b  = bh / NH, h = bh % NH, u = h / GRP;

    const size_t qbase = (size_t)(b * NH + h) * S * HD;
    const size_t kbase = (size_t)(b * NKV + u) * S * HD;
    const size_t vbase = (size_t)(b * NKV + u) * HD * S;

    // ---- stage Q hi/lo tiles (swizzled), pull per-wave fragments ----
    {
        unsigned short* QsH = smem;
        unsigned short* QsL = smem + 8192;
#pragma unroll
        for (int i = 0; i < 4; ++i) {
            const int r = (t >> 4) + i * 16;
            const int blk = t & 15;
            const size_t src = qbase + (size_t)(q0 + r) * HD + blk * 8;
            const int dst = r * 128 + ((blk ^ (r & 7)) * 8);
            *reinterpret_cast<short8*>(&QsH[dst]) =
                *reinterpret_cast<const short8*>(&Qh[src]);
            *reinterpret_cast<short8*>(&QsL[dst]) =
                *reinterpret_cast<const short8*>(&Ql[src]);
        }
        __syncthreads();
    }
    short8 qah[4], qal[4];
#pragma unroll
    for (int ks = 0; ks < 4; ++ks) {
        const int qr = w * 16 + lc;
        const int off = qr * 128 + (((ks * 4 + lg) ^ (qr & 7)) * 8);
        qah[ks] = *reinterpret_cast<const short8*>(&smem[off]);
        qal[ks] = *reinterpret_cast<const short8*>(&smem[8192 + off]);
    }
    __syncthreads();   // Q region about to be reused for K/V

    f32x4 o[8];
#pragma unroll
    for (int i = 0; i < 8; ++i) o[i] = (f32x4){0.f, 0.f, 0.f, 0.f};
    float m_run[4] = {-1e30f, -1e30f, -1e30f, -1e30f};
    float l_run[4] = {0.f, 0.f, 0.f, 0.f};

    unsigned short* PwH = PH + w * 640;
    unsigned short* PwL = PL + w * 640;
    const int qw0 = q0 + w * 16;
    const int nkt = q0 / KT + 2;        // k-tiles with k0 < q0+64

    for (int kt = 0; kt < nkt; ++kt) {
        const int k0 = kt * KT;
        // ---- stage K hi/lo [32][128] swizzled ----
#pragma unroll
        for (int i = 0; i < 2; ++i) {
            const int r = (t >> 4) + i * 16;
            const int blk = t & 15;
            const size_t src = kbase + (size_t)(k0 + r) * HD + blk * 8;
            const int dst = r * 128 + ((blk ^ (r & 7)) * 8);
            *reinterpret_cast<short8*>(&KsH[dst]) =
                *reinterpret_cast<const short8*>(&Kh[src]);
            *reinterpret_cast<short8*>(&KsL[dst]) =
                *reinterpret_cast<const short8*>(&Kl[src]);
        }
        // ---- stage V^T hi/lo [128][40] ----
#pragma unroll
        for (int i = 0; i < 2; ++i) {
            const int dv = (t >> 2) + i * 64;
            const int blk = t & 3;
            const size_t src = vbase + (size_t)dv * S + k0 + blk * 8;
            const int dst = dv * 40 + blk * 8;
            *reinterpret_cast<short8*>(&VtH[dst]) =
                *reinterpret_cast<const short8*>(&Vh[src]);
            *reinterpret_cast<short8*>(&VtL[dst]) =
                *reinterpret_cast<const short8*>(&Vl[src]);
        }
        __syncthreads();

        // ---- S = Q.K^T  (hi/lo: 3 mfma per product, 2 col-tiles, 4 ks) ----
        f32x4 a0 = {0.f, 0.f, 0.f, 0.f}, a1 = {0.f, 0.f, 0.f, 0.f};
#pragma unroll
        for (int ks = 0; ks < 4; ++ks) {
            const int r0 = lc, r1 = 16 + lc;
            const int o0b = r0 * 128 + (((ks * 4 + lg) ^ (r0 & 7)) * 8);
            const int o1b = r1 * 128 + (((ks * 4 + lg) ^ (r1 & 7)) * 8);
            const short8 kb0h = *reinterpret_cast<const short8*>(&KsH[o0b]);
            const short8 kb0l = *reinterpret_cast<const short8*>(&KsL[o0b]);
            const short8 kb1h = *reinterpret_cast<const short8*>(&KsH[o1b]);
            const short8 kb1l = *reinterpret_cast<const short8*>(&KsL[o1b]);
            a0 = __builtin_amdgcn_mfma_f32_16x16x32_bf16(qal[ks], kb0h, a0, 0, 0, 0);
            a0 = __builtin_amdgcn_mfma_f32_16x16x32_bf16(qah[ks], kb0l, a0, 0, 0, 0);
            a0 = __builtin_amdgcn_mfma_f32_16x16x32_bf16(qah[ks], kb0h, a0, 0, 0, 0);
            a1 = __builtin_amdgcn_mfma_f32_16x16x32_bf16(qal[ks], kb1h, a1, 0, 0, 0);
            a1 = __builtin_amdgcn_mfma_f32_16x16x32_bf16(qah[ks], kb1l, a1, 0, 0, 0);
            a1 = __builtin_amdgcn_mfma_f32_16x16x32_bf16(qah[ks], kb1h, a1, 0, 0, 0);
        }

        // ---- online softmax (rows m = lg*4+r) ----
        const bool need_mask = (k0 + KT - 1 > qw0);
#pragma unroll
        for (int r = 0; r < 4; ++r) {
            float s0 = a0[r], s1 = a1[r];
            const int qg = qw0 + lg * 4 + r;
            if (need_mask) {
                if (k0 + lc > qg)      s0 = -1e30f;
                if (k0 + 16 + lc > qg) s1 = -1e30f;
            }
            float mx = fmaxf(s0, s1);
            mx = fmaxf(mx, __shfl_xor(mx, 1, 64));
            mx = fmaxf(mx, __shfl_xor(mx, 2, 64));
            mx = fmaxf(mx, __shfl_xor(mx, 4, 64));
            mx = fmaxf(mx, __shfl_xor(mx, 8, 64));
            const float mn  = fmaxf(m_run[r], mx);
            const float rsc = __expf(m_run[r] - mn);
            const float p0  = __expf(s0 - mn);
            const float p1  = __expf(s1 - mn);
            float rs = p0 + p1;
            rs += __shfl_xor(rs, 1, 64);
            rs += __shfl_xor(rs, 2, 64);
            rs += __shfl_xor(rs, 4, 64);
            rs += __shfl_xor(rs, 8, 64);
            l_run[r] = l_run[r] * rsc + rs;
            m_run[r] = mn;
#pragma unroll
            for (int nt = 0; nt < 8; ++nt) o[nt][r] *= rsc;
            const unsigned short p0h = f2bf(p0);
            const unsigned short p1h = f2bf(p1);
            const int row = (lg * 4 + r) * 40;
            PwH[row + lc]      = p0h;
            PwH[row + 16 + lc] = p1h;
            PwL[row + lc]      = f2bf(p0 - bf2f(p0h));
            PwL[row + 16 + lc] = f2bf(p1 - bf2f(p1h));
        }
        asm volatile("s_waitcnt lgkmcnt(0)" ::: "memory");

        // ---- O += P.V  (hi/lo) ----
        const short8 pah = *reinterpret_cast<const short8*>(&PwH[lc * 40 + lg * 8]);
        const short8 pal = *reinterpret_cast<const short8*>(&PwL[lc * 40 + lg * 8]);
#pragma unroll
        for (int nt = 0; nt < 8; ++nt) {
            const int dvo = (nt * 16 + lc) * 40 + lg * 8;
            const short8 vbh = *reinterpret_cast<const short8*>(&VtH[dvo]);
            const short8 vbl = *reinterpret_cast<const short8*>(&VtL[dvo]);
            o[nt] = __builtin_amdgcn_mfma_f32_16x16x32_bf16(pal, vbh, o[nt], 0, 0, 0);
            o[nt] = __builtin_amdgcn_mfma_f32_16x16x32_bf16(pah, vbl, o[nt], 0, 0, 0);
            o[nt] = __builtin_amdgcn_mfma_f32_16x16x32_bf16(pah, vbh, o[nt], 0, 0, 0);
        }
        __syncthreads();
    }

    float invl[4];
#pragma unroll
    for (int r = 0; r < 4; ++r) invl[r] = 1.f / l_run[r];
#pragma unroll
    for (int nt = 0; nt < 8; ++nt) {
#pragma unroll
        for (int r = 0; r < 4; ++r) {
            Om[(size_t)(b * S + qw0 + lg * 4 + r) * (NH * HD) + h * HD + nt * 16 + lc]
                = o[nt][r] * invl[r];
        }
    }
}

} // anonymous namespace

// ---------------------------------------------------------------------------
// Workspace (fp32): q 33.5M | k 8.4M | v 8.4M ; (bf16 hi/lo): q 33.5M |
// k 8.4M | v 8.4M  -> ~101 MB. attn output reuses q_ws.
// ---------------------------------------------------------------------------
extern "C" void kernel_launch(void* const* d_in, const int* in_sizes, int n_in,
                              void* d_out, int out_size, void* d_ws, size_t ws_size,
                              hipStream_t stream)
{
    const float* hidden = (const float*)d_in[0];
    const float* Wq = (const float*)d_in[2];
    const float* Wk = (const float*)d_in[3];
    const float* Wv = (const float*)d_in[4];
    const float* Wo = (const float*)d_in[5];
    float* out = (float*)d_out;

    const int MR = B * S;                         // 4096
    const size_t QE = (size_t)MR * NH * HD;       // 8388608
    const size_t KE = (size_t)MR * NKV * HD;      // 2097152

    float* q_ws = (float*)d_ws;
    float* k_ws = q_ws + QE;
    float* v_ws = k_ws + KE;
    unsigned short* q_hi = (unsigned short*)(v_ws + KE);
    unsigned short* q_lo = q_hi + QE;
    unsigned short* k_hi = q_lo + QE;
    unsigned short* k_lo = k_hi + KE;
    unsigned short* v_hi = k_lo + KE;
    unsigned short* v_lo = v_hi + KE;
    float* attn_ws = q_ws;  // q_ws dead after rope_cast

    const dim3 blk(256);

    sgemm_kernel<<<dim3((NH * HD) / BN, MR / BM), blk, 0, stream>>>(
        hidden, Wq, q_ws, MR, NH * HD, D);
    sgemm_kernel<<<dim3((NKV * HD) / BN, MR / BM), blk, 0, stream>>>(
        hidden, Wk, k_ws, MR, NKV * HD, D);
    sgemm_kernel<<<dim3((NKV * HD) / BN, MR / BM), blk, 0, stream>>>(
        hidden, Wv, v_ws, MR, NKV * HD, D);

    const int qpairs = MR * NH * 64;
    const int kpairs = MR * NKV * 64;
    rope_cast_kernel<<<dim3((qpairs + 255) / 256), blk, 0, stream>>>(
        q_ws, q_hi, q_lo, NH, qpairs, 0.08838834764831845f);
    rope_cast_kernel<<<dim3((kpairs + 255) / 256), blk, 0, stream>>>(
        k_ws, k_hi, k_lo, NKV, kpairs, 1.0f);
    vcast_kernel<<<dim3(S / 64, HD / 64, B * NKV), blk, 0, stream>>>(
        v_ws, v_hi, v_lo);

    flash_mfma_kernel<<<dim3(S / QTILE, B * NH), blk, 0, stream>>>(
        q_hi, q_lo, k_hi, k_lo, v_hi, v_lo, attn_ws);

    sgemm_kernel<<<dim3(D / BN, MR / BM), blk, 0, stream>>>(
        attn_ws, Wo, out, MR, D, D);
}

// Round 4
// 807.285 us; speedup vs baseline: 4.3350x; 2.3149x over previous
//
#include <hip/hip_runtime.h>
#include <math.h>

namespace {

constexpr int B   = 2;
constexpr int S   = 2048;
constexpr int D   = 2048;
constexpr int NH  = 16;
constexpr int NKV = 4;
constexpr int HD  = 128;
constexpr int GRP = NH / NKV;   // 4

typedef __attribute__((ext_vector_type(8))) short  short8;
typedef __attribute__((ext_vector_type(4))) float  f32x4;
typedef unsigned short u16;

__device__ inline u16 f2bf(float f) {
    unsigned u = __float_as_uint(f);
    u = (u + 0x7FFFu + ((u >> 16) & 1u)) >> 16;   // RNE
    return (u16)u;
}
__device__ inline float bf2f(u16 h) {
    return __uint_as_float((unsigned)h << 16);
}

// async global->LDS, 16B per lane; LDS dest = wave-uniform base + lane*16.
__device__ __forceinline__ void gload_lds16(const void* g, void* l) {
    __builtin_amdgcn_global_load_lds(
        (const __attribute__((address_space(1))) unsigned int*)g,
        (__attribute__((address_space(3))) unsigned int*)l, 16, 0, 0);
}

// ---------------------------------------------------------------------------
// split-cast fp32 -> (bf16 hi, bf16 lo), elementwise, float4-vectorized.
// ---------------------------------------------------------------------------
__global__ __launch_bounds__(256)
void split_cast_kernel(const float* __restrict__ X, u16* __restrict__ H,
                       u16* __restrict__ L, int n4)
{
    const int idx = blockIdx.x * 256 + threadIdx.x;
    if (idx >= n4) return;
    const float4 v = reinterpret_cast<const float4*>(X)[idx];
    ushort4 h, l;
    h.x = f2bf(v.x); l.x = f2bf(v.x - bf2f(h.x));
    h.y = f2bf(v.y); l.y = f2bf(v.y - bf2f(h.y));
    h.z = f2bf(v.z); l.z = f2bf(v.z - bf2f(h.z));
    h.w = f2bf(v.w); l.w = f2bf(v.w - bf2f(h.w));
    reinterpret_cast<ushort4*>(H)[idx] = h;
    reinterpret_cast<ushort4*>(L)[idx] = l;
}

// ---------------------------------------------------------------------------
// Weight transpose-cast: W [K=2048][Nw] fp32 -> T hi/lo [n_off+Nw][2048] bf16.
// 64x64 tiles through LDS.
// ---------------------------------------------------------------------------
__global__ __launch_bounds__(256)
void wcast_t_kernel(const float* __restrict__ W, u16* __restrict__ Th,
                    u16* __restrict__ Tl, int Nw, int n_off)
{
    __shared__ u16 th[64][68];
    __shared__ u16 tl[64][68];
    const int t  = threadIdx.x;
    const int n0 = blockIdx.x * 64;
    const int k0 = blockIdx.y * 64;

#pragma unroll
    for (int i = 0; i < 4; ++i) {
        const int kr = (t >> 4) + i * 16;        // k-local row
        const int nc = (t & 15) * 4;             // n-local col
        const float4 v = *reinterpret_cast<const float4*>(
            &W[(size_t)(k0 + kr) * Nw + n0 + nc]);
        const u16 hx = f2bf(v.x), hy = f2bf(v.y), hz = f2bf(v.z), hw = f2bf(v.w);
        th[kr][nc + 0] = hx; tl[kr][nc + 0] = f2bf(v.x - bf2f(hx));
        th[kr][nc + 1] = hy; tl[kr][nc + 1] = f2bf(v.y - bf2f(hy));
        th[kr][nc + 2] = hz; tl[kr][nc + 2] = f2bf(v.z - bf2f(hz));
        th[kr][nc + 3] = hw; tl[kr][nc + 3] = f2bf(v.w - bf2f(hw));
    }
    __syncthreads();
#pragma unroll
    for (int i = 0; i < 4; ++i) {
        const int nr = (t >> 4) + i * 16;        // n-local row (dest)
        const int kc = (t & 15) * 4;             // k-local col (dest)
        ushort4 oh, ol;
        oh.x = th[kc + 0][nr]; ol.x = tl[kc + 0][nr];
        oh.y = th[kc + 1][nr]; ol.y = tl[kc + 1][nr];
        oh.z = th[kc + 2][nr]; ol.z = tl[kc + 2][nr];
        oh.w = th[kc + 3][nr]; ol.w = tl[kc + 3][nr];
        const size_t o = (size_t)(n_off + n0 + nr) * 2048 + k0 + kc;
        *reinterpret_cast<ushort4*>(&Th[o]) = oh;
        *reinterpret_cast<ushort4*>(&Tl[o]) = ol;
    }
}

// ---------------------------------------------------------------------------
// hi/lo double-bf16 MFMA GEMM: C = A.B^T, fp32 out.
// A hi/lo [M][K] bf16, Bt hi/lo [N][K] bf16, C [M][N] fp32.
// 128x128 tile, BK=32, 4 waves (2x2 of 64x64), 48 MFMA/wave/K-step.
// LDS staged via global_load_lds(16B) with pre-swizzled source; frag reads
// XOR-swizzled (blk ^= (row>>1)&3) -> 2-way conflicts (free).
// ---------------------------------------------------------------------------
__global__ __launch_bounds__(256)
void hgemm_hilo_kernel(const u16* __restrict__ Ah, const u16* __restrict__ Al,
                       const u16* __restrict__ Bth, const u16* __restrict__ Btl,
                       float* __restrict__ C, int M, int N, int K)
{
    __shared__ alignas(16) u16 AsH[4096];
    __shared__ alignas(16) u16 AsL[4096];
    __shared__ alignas(16) u16 BsH[4096];
    __shared__ alignas(16) u16 BsL[4096];

    const int t  = threadIdx.x;
    const int w  = t >> 6;
    const int l  = t & 63;
    const int lc = l & 15;
    const int kg = l >> 4;              // 0..3
    const int wr = w >> 1, wc = w & 1;  // 2x2 wave grid

    const int m0 = blockIdx.y * 128;
    const int n0 = blockIdx.x * 128;

    const int srow = l >> 2;            // staging row within 16-row chunk
    const int sblk = l & 3;             // staging 16B block within row

    f32x4 acc[4][4];
#pragma unroll
    for (int i = 0; i < 4; ++i)
#pragma unroll
        for (int j = 0; j < 4; ++j) acc[i][j] = (f32x4){0.f, 0.f, 0.f, 0.f};

    for (int k0 = 0; k0 < K; k0 += 32) {
#pragma unroll
        for (int i = 0; i < 2; ++i) {
            const int c   = i * 4 + w;            // 16-row chunk 0..7
            const int row = c * 16 + srow;
            const int swb = sblk ^ ((row >> 1) & 3);
            const size_t ga = (size_t)(m0 + row) * K + k0 + swb * 8;
            const size_t gb = (size_t)(n0 + row) * K + k0 + swb * 8;
            u16* ldst = (u16*)nullptr;
            (void)ldst;
            gload_lds16(Ah  + ga, AsH + c * 512);
            gload_lds16(Al  + ga, AsL + c * 512);
            gload_lds16(Bth + gb, BsH + c * 512);
            gload_lds16(Btl + gb, BsL + c * 512);
        }
        __syncthreads();

        short8 fah[4], fal[4], fbh[4], fbl[4];
#pragma unroll
        for (int i = 0; i < 4; ++i) {
            const int ra = wr * 64 + i * 16 + lc;
            const int oa = ra * 32 + ((kg ^ ((ra >> 1) & 3)) * 8);
            fah[i] = *reinterpret_cast<const short8*>(&AsH[oa]);
            fal[i] = *reinterpret_cast<const short8*>(&AsL[oa]);
            const int rb = wc * 64 + i * 16 + lc;
            const int ob = rb * 32 + ((kg ^ ((rb >> 1) & 3)) * 8);
            fbh[i] = *reinterpret_cast<const short8*>(&BsH[ob]);
            fbl[i] = *reinterpret_cast<const short8*>(&BsL[ob]);
        }
#pragma unroll
        for (int i = 0; i < 4; ++i)
#pragma unroll
            for (int j = 0; j < 4; ++j) {
                acc[i][j] = __builtin_amdgcn_mfma_f32_16x16x32_bf16(
                    fal[i], fbh[j], acc[i][j], 0, 0, 0);
                acc[i][j] = __builtin_amdgcn_mfma_f32_16x16x32_bf16(
                    fah[i], fbl[j], acc[i][j], 0, 0, 0);
                acc[i][j] = __builtin_amdgcn_mfma_f32_16x16x32_bf16(
                    fah[i], fbh[j], acc[i][j], 0, 0, 0);
            }
        __syncthreads();
    }

#pragma unroll
    for (int i = 0; i < 4; ++i)
#pragma unroll
        for (int j = 0; j < 4; ++j)
#pragma unroll
            for (int r = 0; r < 4; ++r) {
                const int m = m0 + wr * 64 + i * 16 + kg * 4 + r;
                const int n = n0 + wc * 64 + j * 16 + lc;
                C[(size_t)m * N + n] = acc[i][j][r];
            }
}

// ---------------------------------------------------------------------------
// RoPE + split-cast fp32 -> bf16 hi/lo, head-major [B][nh][S][HD].
// Reads from the fused QKV fp32 buffer (stride/col_off).
// ---------------------------------------------------------------------------
__global__ __launch_bounds__(256)
void rope_cast_kernel(const float* __restrict__ X, int stride, int col_off,
                      u16* __restrict__ Yh, u16* __restrict__ Yl,
                      int n_heads, int total_pairs, float scale)
{
    const int idx = blockIdx.x * 256 + threadIdx.x;
    if (idx >= total_pairs) return;
    const int i    = idx & 63;
    const int rest = idx >> 6;
    const int head = rest % n_heads;
    const int row  = rest / n_heads;     // b*S + s
    const int s    = row & (S - 1);
    const int b    = row >> 11;

    const float inv = expf(-9.2103403719761836f * (float)i * (1.0f / 64.0f));
    float sn, cs;
    sincosf((float)s * inv, &sn, &cs);

    const float* src = X + (size_t)row * stride + col_off + head * HD + i;
    const float x1 = src[0], x2 = src[64];
    const float y1 = (x1 * cs - x2 * sn) * scale;
    const float y2 = (x2 * cs + x1 * sn) * scale;

    const u16 h1 = f2bf(y1), h2 = f2bf(y2);
    const size_t o = ((size_t)(b * n_heads + head) * S + s) * HD + i;
    Yh[o] = h1;  Yh[o + 64] = h2;
    Yl[o]      = f2bf(y1 - bf2f(h1));
    Yl[o + 64] = f2bf(y2 - bf2f(h2));
}

// ---------------------------------------------------------------------------
// V: fp32 (from fused QKV buffer) -> bf16 hi/lo transposed [B][NKV][HD][S].
// ---------------------------------------------------------------------------
__global__ __launch_bounds__(256)
void vcast_kernel(const float* __restrict__ V, int stride, int col_off,
                  u16* __restrict__ Yh, u16* __restrict__ Yl)
{
    __shared__ u16 th[64][68];
    __shared__ u16 tl[64][68];
    const int t  = threadIdx.x;
    const int s0 = blockIdx.x * 64, dv0 = blockIdx.y * 64;
    const int b  = blockIdx.z >> 2, u = blockIdx.z & 3;

#pragma unroll
    for (int i = 0; i < 4; ++i) {
        const int sr = (t >> 4) + i * 16;
        const int dc = (t & 15) * 4;
        const float4 v = *reinterpret_cast<const float4*>(
            &V[(size_t)(b * S + s0 + sr) * stride + col_off + u * HD + dv0 + dc]);
        const u16 hx = f2bf(v.x), hy = f2bf(v.y), hz = f2bf(v.z), hw = f2bf(v.w);
        th[sr][dc + 0] = hx; tl[sr][dc + 0] = f2bf(v.x - bf2f(hx));
        th[sr][dc + 1] = hy; tl[sr][dc + 1] = f2bf(v.y - bf2f(hy));
        th[sr][dc + 2] = hz; tl[sr][dc + 2] = f2bf(v.z - bf2f(hz));
        th[sr][dc + 3] = hw; tl[sr][dc + 3] = f2bf(v.w - bf2f(hw));
    }
    __syncthreads();
#pragma unroll
    for (int i = 0; i < 4; ++i) {
        const int dr = (t >> 4) + i * 16;
        const int sc = (t & 15) * 4;
        ushort4 oh, ol;
        oh.x = th[sc + 0][dr]; ol.x = tl[sc + 0][dr];
        oh.y = th[sc + 1][dr]; ol.y = tl[sc + 1][dr];
        oh.z = th[sc + 2][dr]; ol.z = tl[sc + 2][dr];
        oh.w = th[sc + 3][dr]; ol.w = tl[sc + 3][dr];
        const size_t o = ((size_t)(b * NKV + u) * HD + dv0 + dr) * S + s0 + sc;
        *reinterpret_cast<ushort4*>(&Yh[o]) = oh;
        *reinterpret_cast<ushort4*>(&Yl[o]) = ol;
    }
}

// ---------------------------------------------------------------------------
// Flash attention, double-bf16 (hi/lo) MFMA, fp32 online softmax.
// (Structure identical to the round-3 passing version; epilogue now emits
// attn directly as bf16 hi/lo for the O-projection GEMM.)
// ---------------------------------------------------------------------------
constexpr int QTILE = 64, KT = 32;

__global__ __launch_bounds__(256)
void flash_mfma_kernel(const u16* __restrict__ Qh, const u16* __restrict__ Ql,
                       const u16* __restrict__ Kh, const u16* __restrict__ Kl,
                       const u16* __restrict__ Vh, const u16* __restrict__ Vl,
                       u16* __restrict__ Oh, u16* __restrict__ Ol)
{
    __shared__ alignas(16) u16 smem[23552];
    u16* KsH = smem;
    u16* KsL = smem + 4096;
    u16* VtH = smem + 8192;
    u16* VtL = smem + 13312;
    u16* PH  = smem + 18432;
    u16* PL  = smem + 20992;

    const int t  = threadIdx.x;
    const int w  = t >> 6;
    const int ln = t & 63;
    const int lg = ln >> 4;             // 0..3
    const int lc = ln & 15;             // 0..15

    const int qt = (int)gridDim.x - 1 - (int)blockIdx.x;   // heavy tiles first
    const int q0 = qt * QTILE;
    const int bh = blockIdx.y;
    const int b  = bh / NH, h = bh % NH, u = h / GRP;

    const size_t qbase = (size_t)(b * NH + h) * S * HD;
    const size_t kbase = (size_t)(b * NKV + u) * S * HD;
    const size_t vbase = (size_t)(b * NKV + u) * HD * S;

    // ---- stage Q hi/lo tiles (swizzled), pull per-wave fragments ----
    {
        u16* QsH = smem;
        u16* QsL = smem + 8192;
#pragma unroll
        for (int i = 0; i < 4; ++i) {
            const int r = (t >> 4) + i * 16;
            const int blk = t & 15;
            const size_t src = qbase + (size_t)(q0 + r) * HD + blk * 8;
            const int dst = r * 128 + ((blk ^ (r & 7)) * 8);
            *reinterpret_cast<short8*>(&QsH[dst]) =
                *reinterpret_cast<const short8*>(&Qh[src]);
            *reinterpret_cast<short8*>(&QsL[dst]) =
                *reinterpret_cast<const short8*>(&Ql[src]);
        }
        __syncthreads();
    }
    short8 qah[4], qal[4];
#pragma unroll
    for (int ks = 0; ks < 4; ++ks) {
        const int qr = w * 16 + lc;
        const int off = qr * 128 + (((ks * 4 + lg) ^ (qr & 7)) * 8);
        qah[ks] = *reinterpret_cast<const short8*>(&smem[off]);
        qal[ks] = *reinterpret_cast<const short8*>(&smem[8192 + off]);
    }
    __syncthreads();

    f32x4 o[8];
#pragma unroll
    for (int i = 0; i < 8; ++i) o[i] = (f32x4){0.f, 0.f, 0.f, 0.f};
    float m_run[4] = {-1e30f, -1e30f, -1e30f, -1e30f};
    float l_run[4] = {0.f, 0.f, 0.f, 0.f};

    u16* PwH = PH + w * 640;
    u16* PwL = PL + w * 640;
    const int qw0 = q0 + w * 16;
    const int nkt = q0 / KT + 2;

    for (int kt = 0; kt < nkt; ++kt) {
        const int k0 = kt * KT;
#pragma unroll
        for (int i = 0; i < 2; ++i) {
            const int r = (t >> 4) + i * 16;
            const int blk = t & 15;
            const size_t src = kbase + (size_t)(k0 + r) * HD + blk * 8;
            const int dst = r * 128 + ((blk ^ (r & 7)) * 8);
            *reinterpret_cast<short8*>(&KsH[dst]) =
                *reinterpret_cast<const short8*>(&Kh[src]);
            *reinterpret_cast<short8*>(&KsL[dst]) =
                *reinterpret_cast<const short8*>(&Kl[src]);
        }
#pragma unroll
        for (int i = 0; i < 2; ++i) {
            const int dv = (t >> 2) + i * 64;
            const int blk = t & 3;
            const size_t src = vbase + (size_t)dv * S + k0 + blk * 8;
            const int dst = dv * 40 + blk * 8;
            *reinterpret_cast<short8*>(&VtH[dst]) =
                *reinterpret_cast<const short8*>(&Vh[src]);
            *reinterpret_cast<short8*>(&VtL[dst]) =
                *reinterpret_cast<const short8*>(&Vl[src]);
        }
        __syncthreads();

        f32x4 a0 = {0.f, 0.f, 0.f, 0.f}, a1 = {0.f, 0.f, 0.f, 0.f};
#pragma unroll
        for (int ks = 0; ks < 4; ++ks) {
            const int r0 = lc, r1 = 16 + lc;
            const int o0b = r0 * 128 + (((ks * 4 + lg) ^ (r0 & 7)) * 8);
            const int o1b = r1 * 128 + (((ks * 4 + lg) ^ (r1 & 7)) * 8);
            const short8 kb0h = *reinterpret_cast<const short8*>(&KsH[o0b]);
            const short8 kb0l = *reinterpret_cast<const short8*>(&KsL[o0b]);
            const short8 kb1h = *reinterpret_cast<const short8*>(&KsH[o1b]);
            const short8 kb1l = *reinterpret_cast<const short8*>(&KsL[o1b]);
            a0 = __builtin_amdgcn_mfma_f32_16x16x32_bf16(qal[ks], kb0h, a0, 0, 0, 0);
            a0 = __builtin_amdgcn_mfma_f32_16x16x32_bf16(qah[ks], kb0l, a0, 0, 0, 0);
            a0 = __builtin_amdgcn_mfma_f32_16x16x32_bf16(qah[ks], kb0h, a0, 0, 0, 0);
            a1 = __builtin_amdgcn_mfma_f32_16x16x32_bf16(qal[ks], kb1h, a1, 0, 0, 0);
            a1 = __builtin_amdgcn_mfma_f32_16x16x32_bf16(qah[ks], kb1l, a1, 0, 0, 0);
            a1 = __builtin_amdgcn_mfma_f32_16x16x32_bf16(qah[ks], kb1h, a1, 0, 0, 0);
        }

        const bool need_mask = (k0 + KT - 1 > qw0);
#pragma unroll
        for (int r = 0; r < 4; ++r) {
            float s0 = a0[r], s1 = a1[r];
            const int qg = qw0 + lg * 4 + r;
            if (need_mask) {
                if (k0 + lc > qg)      s0 = -1e30f;
                if (k0 + 16 + lc > qg) s1 = -1e30f;
            }
            float mx = fmaxf(s0, s1);
            mx = fmaxf(mx, __shfl_xor(mx, 1, 64));
            mx = fmaxf(mx, __shfl_xor(mx, 2, 64));
            mx = fmaxf(mx, __shfl_xor(mx, 4, 64));
            mx = fmaxf(mx, __shfl_xor(mx, 8, 64));
            const float mn  = fmaxf(m_run[r], mx);
            const float rsc = __expf(m_run[r] - mn);
            const float p0  = __expf(s0 - mn);
            const float p1  = __expf(s1 - mn);
            float rs = p0 + p1;
            rs += __shfl_xor(rs, 1, 64);
            rs += __shfl_xor(rs, 2, 64);
            rs += __shfl_xor(rs, 4, 64);
            rs += __shfl_xor(rs, 8, 64);
            l_run[r] = l_run[r] * rsc + rs;
            m_run[r] = mn;
#pragma unroll
            for (int nt = 0; nt < 8; ++nt) o[nt][r] *= rsc;
            const u16 p0h = f2bf(p0);
            const u16 p1h = f2bf(p1);
            const int row = (lg * 4 + r) * 40;
            PwH[row + lc]      = p0h;
            PwH[row + 16 + lc] = p1h;
            PwL[row + lc]      = f2bf(p0 - bf2f(p0h));
            PwL[row + 16 + lc] = f2bf(p1 - bf2f(p1h));
        }
        asm volatile("s_waitcnt lgkmcnt(0)" ::: "memory");

        const short8 pah = *reinterpret_cast<const short8*>(&PwH[lc * 40 + lg * 8]);
        const short8 pal = *reinterpret_cast<const short8*>(&PwL[lc * 40 + lg * 8]);
#pragma unroll
        for (int nt = 0; nt < 8; ++nt) {
            const int dvo = (nt * 16 + lc) * 40 + lg * 8;
            const short8 vbh = *reinterpret_cast<const short8*>(&VtH[dvo]);
            const short8 vbl = *reinterpret_cast<const short8*>(&VtL[dvo]);
            o[nt] = __builtin_amdgcn_mfma_f32_16x16x32_bf16(pal, vbh, o[nt], 0, 0, 0);
            o[nt] = __builtin_amdgcn_mfma_f32_16x16x32_bf16(pah, vbl, o[nt], 0, 0, 0);
            o[nt] = __builtin_amdgcn_mfma_f32_16x16x32_bf16(pah, vbh, o[nt], 0, 0, 0);
        }
        __syncthreads();
    }

    float invl[4];
#pragma unroll
    for (int r = 0; r < 4; ++r) invl[r] = 1.f / l_run[r];
#pragma unroll
    for (int nt = 0; nt < 8; ++nt) {
#pragma unroll
        for (int r = 0; r < 4; ++r) {
            const float v = o[nt][r] * invl[r];
            const size_t off =
                (size_t)(b * S + qw0 + lg * 4 + r) * (NH * HD) + h * HD + nt * 16 + lc;
            const u16 hv = f2bf(v);
            Oh[off] = hv;
            Ol[off] = f2bf(v - bf2f(hv));
        }
    }
}

} // anonymous namespace

// ---------------------------------------------------------------------------
// Workspace (byte offsets), 120 MiB total with aliasing:
//   [0,16.78M)    hid_hi  -> (after GEMM1) q_hi
//   [16.78,33.55) hid_lo  -> q_lo
//   [33.55,83.89) qkv fp32 [4096][3072] -> (after casts) attn_hi/attn_lo
//   [83.89,100.66) k_hi k_lo v_hi v_lo (post-rope, 4.19M each)
//   [100.66,125.83) WqkvT hi/lo [3072][2048] -> (after GEMM1) WoT hi/lo
// ---------------------------------------------------------------------------
extern "C" void kernel_launch(void* const* d_in, const int* in_sizes, int n_in,
                              void* d_out, int out_size, void* d_ws, size_t ws_size,
                              hipStream_t stream)
{
    const float* hidden = (const float*)d_in[0];
    const float* Wq = (const float*)d_in[2];
    const float* Wk = (const float*)d_in[3];
    const float* Wv = (const float*)d_in[4];
    const float* Wo = (const float*)d_in[5];
    float* out = (float*)d_out;

    char* wsb = (char*)d_ws;
    u16*   hid_hi  = (u16*)(wsb);
    u16*   hid_lo  = (u16*)(wsb + 16777216);
    float* qkv_f   = (float*)(wsb + 33554432);
    u16*   k_hi    = (u16*)(wsb + 83886080);
    u16*   k_lo    = (u16*)(wsb + 88080384);
    u16*   v_hi    = (u16*)(wsb + 92274688);
    u16*   v_lo    = (u16*)(wsb + 96468992);
    u16*   wT_hi   = (u16*)(wsb + 100663296);
    u16*   wT_lo   = (u16*)(wsb + 113246208);
    // aliases
    u16* q_hi    = hid_hi;                     // hid dead after GEMM1
    u16* q_lo    = hid_lo;
    u16* attn_hi = (u16*)(wsb + 33554432);     // qkv_f dead after rope/vcast
    u16* attn_lo = (u16*)(wsb + 50331648);
    u16* woT_hi  = wT_hi;                      // WqkvT dead after GEMM1
    u16* woT_lo  = wT_lo;

    const dim3 blk(256);

    // hidden -> hi/lo bf16
    split_cast_kernel<<<dim3(8192), blk, 0, stream>>>(hidden, hid_hi, hid_lo, 2097152);
    // W^T casts (QKV fused: rows [0,2048)=Wq, [2048,2560)=Wk, [2560,3072)=Wv)
    wcast_t_kernel<<<dim3(32, 32), blk, 0, stream>>>(Wq, wT_hi, wT_lo, 2048, 0);
    wcast_t_kernel<<<dim3(8, 32),  blk, 0, stream>>>(Wk, wT_hi, wT_lo, 512, 2048);
    wcast_t_kernel<<<dim3(8, 32),  blk, 0, stream>>>(Wv, wT_hi, wT_lo, 512, 2560);
    // fused QKV projection
    hgemm_hilo_kernel<<<dim3(24, 32), blk, 0, stream>>>(
        hid_hi, hid_lo, wT_hi, wT_lo, qkv_f, 4096, 3072, 2048);
    // Wo^T cast (aliases WqkvT; stream-ordered after GEMM1)
    wcast_t_kernel<<<dim3(32, 32), blk, 0, stream>>>(Wo, woT_hi, woT_lo, 2048, 0);
    // RoPE + split-cast (Q pre-scaled by 1/sqrt(HD)), V transpose-cast
    const int qpairs = 4096 * NH * 64;
    const int kpairs = 4096 * NKV * 64;
    rope_cast_kernel<<<dim3(qpairs / 256), blk, 0, stream>>>(
        qkv_f, 3072, 0, q_hi, q_lo, NH, qpairs, 0.08838834764831845f);
    rope_cast_kernel<<<dim3(kpairs / 256), blk, 0, stream>>>(
        qkv_f, 3072, 2048, k_hi, k_lo, NKV, kpairs, 1.0f);
    vcast_kernel<<<dim3(32, 2, 8), blk, 0, stream>>>(
        qkv_f, 3072, 2560, v_hi, v_lo);
    // flash attention -> attn hi/lo bf16
    flash_mfma_kernel<<<dim3(S / QTILE, B * NH), blk, 0, stream>>>(
        q_hi, q_lo, k_hi, k_lo, v_hi, v_lo, attn_hi, attn_lo);
    // O projection
    hgemm_hilo_kernel<<<dim3(16, 32), blk, 0, stream>>>(
        attn_hi, attn_lo, woT_hi, woT_lo, out, 4096, 2048, 2048);
}